// Round 5
// baseline (6846.781 us; speedup 1.0000x reference)
//
#include <hip/hip_runtime.h>
#include <hip/hip_cooperative_groups.h>

namespace cg = cooperative_groups;

#define N_      800
#define C_      64
#define TRS_    40
#define SPT_    10
#define T_      400
#define HIST_   520           // 120 history + 400 produced rows (time-major)
#define KPL     13            // edges per lane: 13*64 = 832 >= 800
#define SENT    0x7FC00BADu   // qNaN sentinel for "not yet written"
#define NEAR_D  4             // d < 4: per-step ALD poll; d >= 4: global ring scatter
#define BATCH   4             // ring batch period (ring span 118+3 < 128 ok)

#define A_F     (-0.5f)
#define OMEGA_F (10.0f)
#define G_F     (500.0f)
#define KGI_F   (5.0f)
#define DT_F    (1e-4f)

#define ALD(p)    __hip_atomic_load((p), __ATOMIC_RELAXED, __HIP_MEMORY_SCOPE_AGENT)
#define AST(p,v)  __hip_atomic_store((p), (v), __ATOMIC_RELAXED, __HIP_MEMORY_SCOPE_AGENT)
#define AADD(p,v) __hip_atomic_fetch_add((p), (v), __ATOMIC_RELAXED, __HIP_MEMORY_SCOPE_AGENT)

// ---------------- prelude kernels (unchanged, proven) ----------------

__global__ void k_sumsq(const float* __restrict__ sc, float* __restrict__ sumsq) {
    __shared__ float sh[4];
    int tid = threadIdx.x;
    int idx = blockIdx.x * 256 + tid;
    float s = 0.f;
    for (int i = idx; i < N_ * N_; i += 256 * 256) { float v = sc[i]; s += v * v; }
    #pragma unroll
    for (int o = 1; o < 64; o <<= 1) s += __shfl_xor(s, o, 64);
    if ((tid & 63) == 0) sh[tid >> 6] = s;
    __syncthreads();
    if (tid == 0) atomicAdd(sumsq, sh[0] + sh[1] + sh[2] + sh[3]);
}

__global__ void k_detect(const int* __restrict__ dw, int* __restrict__ flag) {
    __shared__ int sh[4];
    int tid = threadIdx.x;
    int v = 0;
    for (int idx = 2 * tid + 1; idx < 800; idx += 512) v |= dw[idx];
    #pragma unroll
    for (int o = 1; o < 64; o <<= 1) v |= __shfl_xor(v, o, 64);
    if ((tid & 63) == 0) sh[tid >> 6] = v;
    __syncthreads();
    if (tid == 0) flag[0] = ((sh[0] | sh[1] | sh[2] | sh[3]) == 0) ? 1 : 0; // 1 => int64
}

// time-major state: xg[(120+time)*800 + j] = x_j(time); rows 0..119 from hE, rest SENT
__global__ void k_init(const float* __restrict__ hE, unsigned int* __restrict__ xg) {
    int idx = blockIdx.x * 256 + threadIdx.x;
    if (idx >= HIST_ * N_) return;
    int s = idx / N_, j = idx - s * N_;
    unsigned int v = (s < 120) ? __float_as_uint(hE[j * 120 + (119 - s)]) : SENT;
    xg[idx] = v;
}

// ---------------- main persistent kernel ----------------
// Elastic (NO barriers in main loop). Delay classes:
//   d < 4  : per-step scattered ALD poll (~27 edges/row, 4x fewer than R0)
//   d >= 4 : wave-private GLOBAL ring ringG[i][128], filled by fire-and-forget
//            agent-scope float atomics every 4 steps from source rows [t-5,t-2]
//            (plain cached reads + ALD retry). One vmcnt(0) per batch, then the
//            4 ring slots [t,t+3] are read once into registers and zeroed.
// No LDS atomics, no LDS ring, no block-wide staging.

__global__ void __launch_bounds__(512, 1) k_main(
    const float* __restrict__ sc, const int* __restrict__ dw,
    const float* __restrict__ hx, const float* __restrict__ external,
    const float* __restrict__ noise, const float* __restrict__ lm,
    const float* __restrict__ sumsq, const int* __restrict__ flag,
    unsigned int* __restrict__ xg, float* __restrict__ ringG,
    float* __restrict__ xtr, float* __restrict__ out)
{
    cg::grid_group grid = cg::this_grid();

    const int lane = threadIdx.x & 63;
    const int wid  = threadIdx.x >> 6;
    const int i    = blockIdx.x * 8 + wid;

    const float inv_norm = 1.0f / sqrtf(*sumsq);
    const int is64 = *flag;

    float* ringR = ringG + i * 128;     // wave-private

    // per-lane edge metadata: j = k*64+lane
    float wn[KPL], wf[KPL]; int an[KPL], df[KPL], jj_[KPL];
    float rsum = 0.f;
    #pragma unroll
    for (int k = 0; k < KPL; ++k) {
        int j = k * 64 + lane;
        bool valid = (j < N_);
        jj_[k] = valid ? j : 0;
        int base = i * N_ + jj_[k];
        float wv = valid ? fabsf(sc[base]) * inv_norm : 0.f;
        int dv = valid ? dw[is64 ? (base << 1) : base] : 0;
        rsum += wv;
        wn[k] = (valid && dv < NEAR_D) ? wv : 0.f;
        wf[k] = (valid && dv >= NEAR_D) ? wv : 0.f;
        an[k] = (119 - dv) * N_ + jj_[k];   // + t*N_ -> cell x_j(t-1-d)
        df[k] = 1 + dv;                     // ring target offset from source step
    }
    #pragma unroll
    for (int o = 1; o < 64; o <<= 1) rsum += __shfl_xor(rsum, o, 64);

    // ---- prologue: scatter history sources s in [-120, -6] (never SENT) ----
    #pragma unroll 1
    for (int s = -120; s <= -6; ++s) {
        const unsigned int* row = xg + (120 + s) * N_;
        #pragma unroll
        for (int k = 0; k < KPL; ++k) {
            if (wf[k] != 0.f) {
                int tt = s + df[k];
                if (tt >= 0)
                    AADD(&ringR[tt & 127], wf[k] * __uint_as_float(row[jj_[k]]));
            }
        }
    }

    float x = hx[2 * i], y = hx[2 * i + 1];

    #pragma unroll 1
    for (int tb = 0; tb < T_; tb += BATCH) {
        // ---- batch: read source rows [tb-5, tb-2] (full ILP), scatter to ring ----
        unsigned int sv[BATCH][KPL];
        #pragma unroll
        for (int r = 0; r < BATCH; ++r) {
            const unsigned int* row = xg + (115 + tb + r) * N_;   // s = tb-5+r
            #pragma unroll
            for (int k = 0; k < KPL; ++k)
                sv[r][k] = (wf[k] != 0.f) ? row[jj_[k]] : 0u;     // cached first try
        }
        {
            int g = 0;
            while (true) {
                int pend = 0;
                #pragma unroll
                for (int r = 0; r < BATCH; ++r)
                    #pragma unroll
                    for (int k = 0; k < KPL; ++k) pend |= (sv[r][k] == SENT) ? 1 : 0;
                if (!__any(pend)) break;
                if (++g > 100000000) break;             // safety valve
                #pragma unroll
                for (int r = 0; r < BATCH; ++r) {
                    const unsigned int* row = xg + (115 + tb + r) * N_;
                    #pragma unroll
                    for (int k = 0; k < KPL; ++k)
                        if (sv[r][k] == SENT) sv[r][k] = ALD(&row[jj_[k]]);
                }
            }
        }
        #pragma unroll
        for (int r = 0; r < BATCH; ++r) {
            int s = tb - 5 + r;
            #pragma unroll
            for (int k = 0; k < KPL; ++k)
                if (wf[k] != 0.f)
                    AADD(&ringR[(s + df[k]) & 127], wf[k] * __uint_as_float(sv[r][k]));
        }

        // ---- drain own atomics, then read+zero ring slots [tb, tb+3] ----
        asm volatile("s_waitcnt vmcnt(0)" ::: "memory");
        float fps[BATCH];
        const int rb = tb & 127;                        // tb%4==0 -> no wrap in 4 slots
        #pragma unroll
        for (int r = 0; r < BATCH; ++r) fps[r] = __uint_as_float(ALD((unsigned int*)&ringR[rb + r]));
        if (lane == 0) {
            #pragma unroll
            for (int r = 0; r < BATCH; ++r) AST(&ringR[rb + r], 0.f);
        }

        // ---- 4 integration steps ----
        #pragma unroll
        for (int s4 = 0; s4 < BATCH; ++s4) {
            const int t = tb + s4;
            const int tbase = t * N_;

            // near poll (d<4), proven elastic pattern
            unsigned int vv[KPL];
            #pragma unroll
            for (int k = 0; k < KPL; ++k)
                vv[k] = (wn[k] != 0.f) ? ALD(&xg[an[k] + tbase]) : 0u;
            int g = 0;
            while (true) {
                int pend = 0;
                #pragma unroll
                for (int k = 0; k < KPL; ++k) pend |= (vv[k] == SENT) ? 1 : 0;
                if (!__any(pend)) break;
                if (++g > 100000000) break;             // safety valve
                #pragma unroll
                for (int k = 0; k < KPL; ++k)
                    if (vv[k] == SENT) vv[k] = ALD(&xg[an[k] + tbase]);
            }
            float acc = 0.f;
            #pragma unroll
            for (int k = 0; k < KPL; ++k) acc += wn[k] * __uint_as_float(vv[k]);
            #pragma unroll
            for (int o = 1; o < 64; o <<= 1) acc += __shfl_xor(acc, o, 64);

            float led = acc + fps[s4];

            // integrate / publish
            int tr = (t * 205) >> 11;                   // t/10 for t<400
            int sp = t - tr * 10;
            float u  = external[(i * SPT_ + sp) * TRS_ + tr];
            float n0 = noise[(t * N_ + i) * 2 + 0];
            float n1 = noise[(t * N_ + i) * 2 + 1];

            float r2 = x * x + y * y;
            float dx = (A_F - r2) * x - OMEGA_F * y + G_F * (led - rsum * x) + KGI_F * u;
            float dy = (A_F - r2) * y + OMEGA_F * x;
            x = x + DT_F * dx + n0;
            y = y + DT_F * dy + n1;

            if (lane == 0) {
                AST(&xg[(120 + t) * N_ + i], __float_as_uint(x));
                if (sp == SPT_ - 1) xtr[tr * N_ + i] = x;
            }
        }
    }

    grid.sync();   // make xtr visible for the epilogue

    // epilogue: out[c*TRS + tr] = 5 * dot(xtr[tr,:], lm[c,:]) - 2
    for (int o = i; o < C_ * TRS_; o += 800) {
        int c = o / TRS_, tr = o - c * TRS_;
        float s = 0.f;
        #pragma unroll
        for (int k = 0; k < KPL; ++k) {
            int n = k * 64 + lane;
            if (n < N_) s += xtr[tr * N_ + n] * lm[c * N_ + n];
        }
        #pragma unroll
        for (int o2 = 1; o2 < 64; o2 <<= 1) s += __shfl_xor(s, o2, 64);
        if (lane == 0) out[o] = 5.0f * s - 2.0f;
    }
}

// ---------------- launch ----------------

extern "C" void kernel_launch(void* const* d_in, const int* in_sizes, int n_in,
                              void* d_out, int out_size, void* d_ws, size_t ws_size,
                              hipStream_t stream) {
    const float* external = (const float*)d_in[0];
    const float* hx       = (const float*)d_in[1];
    const float* hE       = (const float*)d_in[2];
    const float* sc       = (const float*)d_in[3];
    const float* lm       = (const float*)d_in[4];
    const float* noise    = (const float*)d_in[5];
    const int*   delays   = (const int*)  d_in[6];
    float* out = (float*)d_out;

    float*        sumsq = (float*)d_ws;                    // ws[0]
    int*          flag  = (int*)d_ws + 1;                  // ws[1]
    unsigned int* xg    = (unsigned int*)d_ws + 64;        // 520*800 words, time-major
    float*        xtr   = (float*)(xg + HIST_ * N_);       // 40*800 floats
    float*        ringG = xtr + TRS_ * N_;                 // 800*128 floats

    hipMemsetAsync(d_ws, 0, 8, stream);
    hipMemsetAsync(ringG, 0, N_ * 128 * sizeof(float), stream);
    k_sumsq<<<256, 256, 0, stream>>>(sc, sumsq);
    k_detect<<<1, 256, 0, stream>>>(delays, flag);
    k_init<<<(HIST_ * N_ + 255) / 256, 256, 0, stream>>>(hE, xg);

    void* args[] = { (void*)&sc, (void*)&delays, (void*)&hx, (void*)&external,
                     (void*)&noise, (void*)&lm, (void*)&sumsq, (void*)&flag,
                     (void*)&xg, (void*)&ringG, (void*)&xtr, (void*)&out };
    hipLaunchCooperativeKernel((const void*)k_main, dim3(100), dim3(512), args, 0, stream);
}